// Round 12
// baseline (128.334 us; speedup 1.0000x reference)
//
#include <hip/hip_runtime.h>

typedef float fx4 __attribute__((ext_vector_type(4)));
typedef float fx2 __attribute__((ext_vector_type(2)));
typedef short bfrag __attribute__((ext_vector_type(8)));
typedef float ffrag __attribute__((ext_vector_type(4)));
typedef unsigned short ush;

#define NTOK  1024
#define NHEADS 12
#define HD    64
#define DIMM  768

// ---------------- bf16 helpers (bit-level, RNE) ----------------
__device__ __forceinline__ float b2f(ush u) {
  union { unsigned i; float f; } x; x.i = ((unsigned)u) << 16; return x.f;
}
__device__ __forceinline__ ush f2b(float f) {
  union { float f; unsigned i; } x; x.f = f;
  unsigned r = x.i + 0x7fff + ((x.i >> 16) & 1);
  return (ush)(r >> 16);
}

__device__ __forceinline__ void gload16(const void* g, void* l) {
  __builtin_amdgcn_global_load_lds(
      (const __attribute__((address_space(1))) unsigned*)g,
      (__attribute__((address_space(3))) unsigned*)l, 16, 0, 0);
}

__device__ __forceinline__ ffrag mfma16(bfrag a, bfrag b, ffrag c) {
  return __builtin_amdgcn_mfma_f32_16x16x32_bf16(a, b, c, 0, 0, 0);
}

// counted vmcnt wait (T4). N = outstanding VMEM ops allowed to remain.
template<int N> __device__ __forceinline__ void vwait() {
  if constexpr (N == 0)       asm volatile("s_waitcnt vmcnt(0)" ::: "memory");
  else if constexpr (N == 1)  asm volatile("s_waitcnt vmcnt(1)" ::: "memory");
  else if constexpr (N == 2)  asm volatile("s_waitcnt vmcnt(2)" ::: "memory");
  else if constexpr (N == 3)  asm volatile("s_waitcnt vmcnt(3)" ::: "memory");
  else if constexpr (N == 4)  asm volatile("s_waitcnt vmcnt(4)" ::: "memory");
  else if constexpr (N == 6)  asm volatile("s_waitcnt vmcnt(6)" ::: "memory");
  else if constexpr (N == 8)  asm volatile("s_waitcnt vmcnt(8)" ::: "memory");
  else if constexpr (N == 12) asm volatile("s_waitcnt vmcnt(12)" ::: "memory");
  else                        asm volatile("s_waitcnt vmcnt(24)" ::: "memory");
}
// raw barrier (no vmcnt drain) with compiler memory fences
__device__ __forceinline__ void bar() {
  asm volatile("" ::: "memory");
  __builtin_amdgcn_s_barrier();
  asm volatile("" ::: "memory");
}
// barrier that first drains own LDS ops (for ds_write -> cross-wave read)
__device__ __forceinline__ void barL() {
  asm volatile("s_waitcnt lgkmcnt(0)" ::: "memory");
  __builtin_amdgcn_s_barrier();
  asm volatile("" ::: "memory");
}

// XOR-swizzled byte address within a [rows][128B] LDS tile (G4 fix).
__device__ __forceinline__ int swz(int row, int b) {
  return row * 128 + (b ^ ((row & 7) << 4));
}

// ---------------------------------------------------------------------------
// k_cvt3: fused fp32 -> (hi,lo) bf16 split for x, qkv_w, proj_w in ONE launch.
// w-lo is never read (qkv is 2-term) -> skip that store.
// ---------------------------------------------------------------------------
__global__ __launch_bounds__(256) void k_cvt3(
    const float* __restrict__ x, const float* __restrict__ w,
    const float* __restrict__ pw,
    ush* __restrict__ xh, ush* __restrict__ xl,
    ush* __restrict__ wh,
    ush* __restrict__ pwh, ush* __restrict__ pwl)
{
  int i = blockIdx.x * 256 + threadIdx.x;
  const float* src; ush *h, *l; int off;
  bool wlo = true;
  if (i < 393216)      { src = x;  h = xh;  l = xl;  off = i; }
  else if (i < 835584) { src = w;  h = wh;  l = nullptr; wlo = false; off = i - 393216; }
  else                 { src = pw; h = pwh; l = pwl; off = i - 835584; }
  fx4 v = *(const fx4*)(src + (size_t)off * 4);
  ushort4 hh, ll;
  float t;
  hh.x = f2b(v[0]); t = v[0] - b2f(hh.x); ll.x = f2b(t);
  hh.y = f2b(v[1]); t = v[1] - b2f(hh.y); ll.y = f2b(t);
  hh.z = f2b(v[2]); t = v[2] - b2f(hh.z); ll.z = f2b(t);
  hh.w = f2b(v[3]); t = v[3] - b2f(hh.w); ll.w = f2b(t);
  *(ushort4*)(h + (size_t)off * 4) = hh;
  if (wlo) *(ushort4*)(l + (size_t)off * 4) = ll;
}

// ---------------------------------------------------------------------------
// 2-buffer counted-vmcnt bf16 NT-GEMM core (BK=32) — used by proj (NTERM=3).
// ---------------------------------------------------------------------------
template<int MR, int NR, int NTERM>
__device__ __forceinline__ void gemm_pipe(
    const ush* __restrict__ Ah, const ush* __restrict__ Al,
    const ush* __restrict__ Bh, const ush* __restrict__ Bl,
    int row0, int col0, int K, short* lds, ffrag (&acc)[MR][NR])
{
  constexpr int F = (NTERM == 3) ? 4 * (MR + NR) : (4 * MR + 2 * NR);
  constexpr int LPS = F / 4;
  static_assert(F % 4 == 0, "frag count must be divisible by wave count");
  const int tid = threadIdx.x;
  const int lane = tid & 63, w = tid >> 6;
  const int wr = w >> 1, wc = w & 1;
  const int l15 = lane & 15, l8 = (lane >> 4) * 8;

  auto stage = [&](short* buf, int k0) {
    #pragma unroll
    for (int i = 0; i < LPS; i++) {
      int f = i * 4 + w;
      const ush* src;
      if (f < 2 * MR)
        src = Ah + (size_t)(row0 + f * 16 + l15) * K + k0 + l8;
      else if (f < 4 * MR)
        src = Al + (size_t)(row0 + (f - 2 * MR) * 16 + l15) * K + k0 + l8;
      else if (f < 4 * MR + 2 * NR)
        src = Bh + (size_t)(col0 + (f - 4 * MR) * 16 + l15) * K + k0 + l8;
      else
        src = Bl + (size_t)(col0 + (f - 4 * MR - 2 * NR) * 16 + l15) * K + k0 + l8;
      gload16(src, buf + f * 512);
    }
  };

  auto step = [&](const short* buf) {
    bfrag ah[MR], al[MR], bh[NR];
    #pragma unroll
    for (int i = 0; i < MR; i++) {
      ah[i] = *(const bfrag*)(buf + (wr * MR + i) * 512 + lane * 8);
      al[i] = *(const bfrag*)(buf + (2 * MR + wr * MR + i) * 512 + lane * 8);
    }
    #pragma unroll
    for (int j = 0; j < NR; j++)
      bh[j] = *(const bfrag*)(buf + (4 * MR + wc * NR + j) * 512 + lane * 8);
    if constexpr (NTERM == 3) {
      bfrag bl[NR];
      #pragma unroll
      for (int j = 0; j < NR; j++)
        bl[j] = *(const bfrag*)(buf + (4 * MR + 2 * NR + wc * NR + j) * 512 + lane * 8);
      #pragma unroll
      for (int i = 0; i < MR; i++)
        #pragma unroll
        for (int j = 0; j < NR; j++) {
          acc[i][j] = mfma16(ah[i], bh[j], acc[i][j]);
          acc[i][j] = mfma16(ah[i], bl[j], acc[i][j]);
          acc[i][j] = mfma16(al[i], bh[j], acc[i][j]);
        }
    } else {
      #pragma unroll
      for (int i = 0; i < MR; i++)
        #pragma unroll
        for (int j = 0; j < NR; j++) {
          acc[i][j] = mfma16(ah[i], bh[j], acc[i][j]);
          acc[i][j] = mfma16(al[i], bh[j], acc[i][j]);
        }
    }
  };

  const int nt = K / 32;
  stage(lds, 0);
  for (int t = 0; t < nt; t++) {
    bar();
    if (t + 1 < nt) {
      stage(lds + ((t + 1) & 1) * F * 512, (t + 1) * 32);
      vwait<LPS>();
    } else {
      vwait<0>();
    }
    bar();
    step(lds + (t & 1) * F * 512);
  }
}

// ---------------------------------------------------------------------------
// qkv GEMM: M=2048, N=2304, K=768; tile 128x128 (wave 64x64), 2-TERM, BK=64.
// Round-12 changes vs round 11 (which measured 41.6us, MfmaUtil 12.7%,
// occupancy = 1 block/CU -> per-step fixed overhead dominant):
//  - BK=64: 12 K-steps instead of 24 -> half the barriers/vwaits; prefetch
//    issue-to-wait distance doubles (~2 sub-steps).
//  - staging pointers hoisted into registers, advanced by += 64/step: removes
//    the per-stage 64-bit address recomputation (VALUBusy was 17%).
// LDS = 2 x 48KB = 96KB. Grid 288 (16x18), 2D XCD partition (4x9 per XCD).
// ---------------------------------------------------------------------------
__global__ __launch_bounds__(256) void k_qkv_mfma(
    const ush* __restrict__ xh, const ush* __restrict__ xl,
    const ush* __restrict__ wh,
    const float* __restrict__ bias,
    ush* __restrict__ qo, ush* __restrict__ ko, ush* __restrict__ vo)
{
  __shared__ short lds[2 * 48 * 512];    // 96 KB: 2 buffers x 48KB (BK=64)
  const int orig = blockIdx.x;
  const int xcd = orig & 7, local = orig >> 3;     // 36 blocks per XCD
  const int lm = local & 3, ln = local >> 2;       // 4 x 9 rectangle
  const int bm = (xcd & 3) * 4 + lm;               // 0..15
  const int bn = (xcd >> 2) * 9 + ln;              // 0..17
  const int row0 = bm * 128, col0 = bn * 128;
  const int K = 768;

  const int tid = threadIdx.x;
  const int lane = tid & 63, w = tid >> 6;
  const int wr = w >> 1, wc = w & 1;
  const int l15 = lane & 15, l8 = (lane >> 4) * 8;

  // 48 frags per buffer: fi = kk*24 + f; f<8:Ah, f<16:Al, f<24:Bh; kk = K-half.
  // Thread stages fi = i*4 + w for i in [0,12). Pointers hoisted, += 64/stage.
  const ush* p[12];
  #pragma unroll
  for (int i = 0; i < 12; i++) {
    int fi = i * 4 + w;
    int kk = fi >= 24 ? 1 : 0;
    int f = fi - kk * 24;
    const ush* base;
    if (f < 8)       base = xh + (size_t)(row0 + f * 16 + l15) * K + l8;
    else if (f < 16) base = xl + (size_t)(row0 + (f - 8) * 16 + l15) * K + l8;
    else             base = wh + (size_t)(col0 + (f - 16) * 16 + l15) * K + l8;
    p[i] = base + kk * 32;
  }

  auto stage = [&](short* buf) {
    #pragma unroll
    for (int i = 0; i < 12; i++) {
      gload16(p[i], buf + (i * 4 + w) * 512);
      p[i] += 64;
    }
  };

  ffrag acc[4][4] = {};
  auto substep = [&](const short* buf, int kk) {
    const short* b = buf + kk * 24 * 512;
    bfrag ah[4], al[4], bh[4];
    #pragma unroll
    for (int i = 0; i < 4; i++) {
      ah[i] = *(const bfrag*)(b + (wr * 4 + i) * 512 + lane * 8);
      al[i] = *(const bfrag*)(b + (8 + wr * 4 + i) * 512 + lane * 8);
    }
    #pragma unroll
    for (int j = 0; j < 4; j++)
      bh[j] = *(const bfrag*)(b + (16 + wc * 4 + j) * 512 + lane * 8);
    #pragma unroll
    for (int i = 0; i < 4; i++)
      #pragma unroll
      for (int j = 0; j < 4; j++) {
        acc[i][j] = mfma16(ah[i], bh[j], acc[i][j]);
        acc[i][j] = mfma16(al[i], bh[j], acc[i][j]);
      }
  };

  stage(lds);                            // K 0..63
  for (int t = 0; t < 12; t++) {
    bar();
    if (t + 1 < 12) {
      stage(lds + ((t + 1) & 1) * 48 * 512);
      vwait<12>();                       // stage(t) landed; t+1 in flight
    } else {
      vwait<0>();
    }
    bar();
    const short* buf = lds + (t & 1) * 48 * 512;
    substep(buf, 0);
    substep(buf, 1);
  }

  const int l4 = lane >> 4;
  const int which = col0 / 768;                    // uniform per block
  const int base_head = (col0 - which * 768) >> 6;
  const int head = base_head + wc;                 // uniform per wave
  ush* base = which == 0 ? qo : (which == 1 ? ko : vo);
  #pragma unroll
  for (int mi = 0; mi < 4; mi++)
    #pragma unroll
    for (int ni = 0; ni < 4; ni++) {
      int d = ni * 16 + l15;                       // 0..63 within head
      float bv = bias[col0 + wc * 64 + d];
      #pragma unroll
      for (int r = 0; r < 4; r++) {
        int row = row0 + wr * 64 + mi * 16 + l4 * 4 + r;
        int bb = row >> 10, n = row & 1023;
        base[((size_t)(bb * NHEADS + head) * NTOK + n) * HD + d] =
            f2b(acc[mi][ni][r] + bv);
      }
    }
}

// ---------------------------------------------------------------------------
// proj GEMM: tile 64x64, 3-TERM; grid 384. 2D XCD partition (8x6 per XCD).
// ---------------------------------------------------------------------------
__global__ __launch_bounds__(256) void k_proj_mfma(
    const ush* __restrict__ ah, const ush* __restrict__ al,
    const ush* __restrict__ bh, const ush* __restrict__ bl,
    const float* __restrict__ bias, float* __restrict__ out)
{
  __shared__ short lds[2 * 16 * 512];    // 32 KB double buffer
  const int orig = blockIdx.x;
  const int xcd = orig & 7, local = orig >> 3;     // 48 blocks per XCD
  const int lm = local & 7, ln = local >> 3;       // 8 x 6 rectangle
  const int bm = (xcd & 3) * 8 + lm;               // 0..31
  const int bn = (xcd >> 2) * 6 + ln;              // 0..11
  const int row0 = bm * 64, col0 = bn * 64;
  ffrag acc[2][2] = {};
  gemm_pipe<2, 2, 3>(ah, al, bh, bl, row0, col0, 768, lds, acc);

  const int tid = threadIdx.x, lane = tid & 63, w = tid >> 6;
  const int wr = w >> 1, wc = w & 1;
  const int l15 = lane & 15, l4 = lane >> 4;
  #pragma unroll
  for (int mi = 0; mi < 2; mi++)
    #pragma unroll
    for (int ni = 0; ni < 2; ni++) {
      int col = col0 + wc * 32 + ni * 16 + l15;
      float bv = bias[col];
      #pragma unroll
      for (int r = 0; r < 4; r++) {
        int row = row0 + wr * 32 + mi * 16 + l4 * 4 + r;
        out[(size_t)row * 768 + col] = acc[mi][ni][r] + bv;
      }
    }
}

// ---------------------------------------------------------------------------
// Kernel: rel-pos bias precompute (q bf16). Unchanged.
// ---------------------------------------------------------------------------
__global__ __launch_bounds__(256) void k_rel(
    const ush* __restrict__ qT, const float* __restrict__ rph,
    const float* __restrict__ rpw,
    float* __restrict__ relh, float* __restrict__ relw)
{
  __shared__ float Qs[32][68];
  __shared__ float RhS[32][68];
  __shared__ float RwS[63][68];
  const int bid = blockIdx.x;
  const int pair = bid >> 5;
  const int nt = bid & 31;
  const int nbase = nt * 32;
  const ush* qp = qT + (size_t)pair * NTOK * HD + (size_t)nbase * HD;
  const int tid = threadIdx.x;
  #pragma unroll
  for (int ii = 0; ii < 2; ii++) {
    int f = ii * 256 + tid;
    int r = f >> 4, k4 = f & 15;
    ushort4 t = *(const ushort4*)(qp + (size_t)r * HD + k4 * 4);
    Qs[r][k4*4+0] = b2f(t.x); Qs[r][k4*4+1] = b2f(t.y);
    Qs[r][k4*4+2] = b2f(t.z); Qs[r][k4*4+3] = b2f(t.w);
    *(fx4*)&RhS[r][k4*4] = *(const fx4*)(rph + (size_t)(nt + r) * 64 + k4 * 4);
  }
  #pragma unroll
  for (int ii = 0; ii < 4; ii++) {
    int f = ii * 256 + tid;
    if (f < 1008) {
      int r = f >> 4, k4 = f & 15;
      *(fx4*)&RwS[r][k4*4] = *(const fx4*)(rpw + (size_t)r * 64 + k4 * 4);
    }
  }
  __syncthreads();
  const int nl = tid >> 3, rem = tid & 7;
  #pragma unroll
  for (int rep = 0; rep < 8; rep++) {
    int kidx = rep * 8 + rem;
    int hw = kidx >> 5;
    int k = kidx & 31;
    const float* rrow = hw ? &RwS[nl + 31 - k][0] : &RhS[31 - k][0];
    float sum = 0.f;
    #pragma unroll
    for (int c4 = 0; c4 < 16; c4++) {
      fx4 q = *(const fx4*)&Qs[nl][c4*4];
      fx4 rv = *(const fx4*)&rrow[c4*4];
      sum = fmaf(q[0], rv[0], sum);
      sum = fmaf(q[1], rv[1], sum);
      sum = fmaf(q[2], rv[2], sum);
      sum = fmaf(q[3], rv[3], sum);
    }
    float* dst = (hw ? relw : relh) + (size_t)pair * NTOK * 32 + (size_t)(nbase + nl) * 32 + k;
    *dst = sum;
  }
}

// ---------------------------------------------------------------------------
// MFMA flash attention, SPLIT-KV. Unchanged from round 11.
// ---------------------------------------------------------------------------
__global__ __launch_bounds__(256, 3) void k_attn_mfma(
    const ush* __restrict__ qT, const ush* __restrict__ kT,
    const ush* __restrict__ vT,
    const float* __restrict__ relh, const float* __restrict__ relw,
    ush* __restrict__ oph, ush* __restrict__ opl, float* __restrict__ ml)
{
  __shared__ short Kf[2 * 8 * 512]; // double-buffered K tiles (8KB each)
  __shared__ char VTb[8192];        // V^T [64 d][64 k] bf16, XOR-swizzled rows
  __shared__ char Phb[8192];        // P hi [64 q][64 k] bf16, swizzled
  __shared__ char Plb[8192];        // P lo
  __shared__ float RhS[64][36];     // relh rows for this q-tile

  const int orig = blockIdx.x;
  const int bid = (orig & 7) * 96 + (orig >> 3);   // 768 = 8*96, bijective
  const int ks   = bid & 1;                        // KV half
  const int qt   = (bid >> 1) & 15;
  const int pair = bid >> 5;
  const int q0 = qt * 64;
  const ush* qp = qT + (size_t)pair * NTOK * HD;
  const ush* kp = kT + (size_t)pair * NTOK * HD;
  const ush* vp = vT + (size_t)pair * NTOK * HD;
  const float* rhp = relh + (size_t)pair * NTOK * 32;
  const float* rwp = relw + (size_t)pair * NTOK * 32;

  const int tid = threadIdx.x;
  const int lane = tid & 63, w = tid >> 6;
  const int l15 = lane & 15, l4 = lane >> 4;
  const int wq = w * 16;
  const int kv = tid & 63, db = tid >> 6;

  auto issueK = [&](int tt) {
    const int gt = ks * 8 + tt;
    const ush* s0 = kp + (size_t)(gt * 64 + wq + l15) * HD + l4 * 8;
    short* dst = Kf + (tt & 1) * 4096 + (w * 2) * 512;
    gload16(s0, dst);
    gload16(s0 + 32, dst + 512);
  };
  auto issueV = [&](int tt, ushort4 (&vr)[4]) {
    const int gt = ks * 8 + tt;
    #pragma unroll
    for (int j = 0; j < 4; j++)
      vr[j] = *(const ushort4*)(vp + (size_t)(gt * 64 + kv) * HD + db * 16 + j * 4);
  };
  auto writeVT = [&](ushort4 (&vr)[4]) {
    #pragma unroll
    for (int j = 0; j < 4; j++) {
      int d0 = db * 16 + j * 4;
      *(ush*)(VTb + swz(d0 + 0, 2 * kv)) = vr[j].x;
      *(ush*)(VTb + swz(d0 + 1, 2 * kv)) = vr[j].y;
      *(ush*)(VTb + swz(d0 + 2, 2 * kv)) = vr[j].z;
      *(ush*)(VTb + swz(d0 + 3, 2 * kv)) = vr[j].w;
    }
  };

  // ---- prologue ----
  {
    int row = tid >> 2, seg = tid & 3;
    const float* src = rhp + (size_t)(q0 + row) * 32 + seg * 8;
    *(fx4*)&RhS[row][seg * 8]     = *(const fx4*)src;
    *(fx4*)&RhS[row][seg * 8 + 4] = *(const fx4*)(src + 4);
  }
  bfrag qf[2];
  qf[0] = *(const bfrag*)(qp + (size_t)(q0 + wq + l15) * HD + l4 * 8);
  qf[1] = *(const bfrag*)(qp + (size_t)(q0 + wq + l15) * HD + 32 + l4 * 8);
  float rw[4][2];
  #pragma unroll
  for (int r = 0; r < 4; r++)
    #pragma unroll
    for (int h = 0; h < 2; h++)
      rw[r][h] = rwp[(size_t)(q0 + wq + l4 * 4 + r) * 32 + h * 16 + l15];

  asm volatile("" ::: "memory");
  ushort4 vrA[4], vrB[4];
  issueK(0); issueV(0, vrA); issueV(1, vrB);

  ffrag o[4] = {};
  float mrow[4] = {-3e38f, -3e38f, -3e38f, -3e38f};
  float lrow[4] = {};

  for (int tt = 0; tt < 8; tt++) {
    const int t = ks * 8 + tt;                 // global tile index (for bias)
    if (tt < 7) vwait<4>(); else vwait<0>();
    barL();   // K(tt) visible; all waves finished iteration tt-1 entirely

    if ((tt & 1) == 0) {
      writeVT(vrA);
      if (tt < 7) issueK(tt + 1);
      if (tt < 6) issueV(tt + 2, vrA);
    } else {
      writeVT(vrB);
      if (tt < 7) issueK(tt + 1);
      if (tt < 6) issueV(tt + 2, vrB);
    }

    // --- QK^T from Kf[tt&1]
    const short* kbuf = Kf + (tt & 1) * 4096;
    ffrag s[4] = {};
    #pragma unroll
    for (int kf = 0; kf < 4; kf++) {
      bfrag kf0 = *(const bfrag*)(kbuf + (kf * 2 + 0) * 512 + lane * 8);
      bfrag kf1 = *(const bfrag*)(kbuf + (kf * 2 + 1) * 512 + lane * 8);
      s[kf] = mfma16(qf[0], kf0, s[kf]);
      s[kf] = mfma16(qf[1], kf1, s[kf]);
    }

    // --- bias + online softmax
    fx2 rh2[4];
    #pragma unroll
    for (int r = 0; r < 4; r++)
      rh2[r] = *(const fx2*)&RhS[wq + l4 * 4 + r][2 * t];
    float pm[4] = {-3e38f, -3e38f, -3e38f, -3e38f};
    #pragma unroll
    for (int kf = 0; kf < 4; kf++)
      #pragma unroll
      for (int r = 0; r < 4; r++) {
        float sc = fmaf(s[kf][r], 0.125f, rh2[r][kf >> 1] + rw[r][kf & 1]);
        s[kf][r] = sc;
        pm[r] = fmaxf(pm[r], sc);
      }
    #pragma unroll
    for (int off = 1; off < 16; off <<= 1)
      #pragma unroll
      for (int r = 0; r < 4; r++)
        pm[r] = fmaxf(pm[r], __shfl_xor(pm[r], off));
    float al[4], ps[4] = {0.f, 0.f, 0.f, 0.f};
    #pragma unroll
    for (int r = 0; r < 4; r++) {
      float mnew = fmaxf(mrow[r], pm[r]);
      al[r] = __expf(mrow[r] - mnew);
      mrow[r] = mnew;
    }
    #pragma unroll
    for (int kf = 0; kf < 4; kf++)
      #pragma unroll
      for (int r = 0; r < 4; r++) {
        float p = __expf(s[kf][r] - mrow[r]);
        s[kf][r] = p;
        ps[r] += p;
      }
    #pragma unroll
    for (int off = 1; off < 16; off <<= 1)
      #pragma unroll
      for (int r = 0; r < 4; r++)
        ps[r] += __shfl_xor(ps[r], off);
    #pragma unroll
    for (int r = 0; r < 4; r++)
      lrow[r] = fmaf(lrow[r], al[r], ps[r]);

    // --- P -> bf16 hi/lo
    #pragma unroll
    for (int kf = 0; kf < 4; kf++)
      #pragma unroll
      for (int r = 0; r < 4; r++) {
        ush hi = f2b(s[kf][r]);
        float lo = s[kf][r] - b2f(hi);
        int a = swz(wq + l4 * 4 + r, kf * 32 + 2 * l15);
        *(ush*)(Phb + a) = hi;
        *(ush*)(Plb + a) = f2b(lo);
      }
    #pragma unroll
    for (int df = 0; df < 4; df++)
      #pragma unroll
      for (int r = 0; r < 4; r++)
        o[df][r] *= al[r];

    barL();   // VT + P writes visible before PV

    // --- PV
    bfrag ph[2], pl[2];
    #pragma unroll
    for (int kc = 0; kc < 2; kc++) {
      int a = swz(wq + l15, kc * 64 + l4 * 16);
      ph[kc] = *(const bfrag*)(Phb + a);
      pl[kc] = *(const bfrag*)(Plb + a);
    }
    #pragma unroll
    for (int df = 0; df < 4; df++)
      #pragma unroll
      for (int kc = 0; kc < 2; kc++) {
        bfrag vf = *(const bfrag*)(VTb + swz(df * 16 + l15, kc * 64 + l4 * 16));
        o[df] = mfma16(ph[kc], vf, o[df]);
        o[df] = mfma16(pl[kc], vf, o[df]);
      }
  }

  // --- epilogue: write UNNORMALIZED partial o + (m,l)
  const int part = ((pair << 4) | qt) * 2 + ks;
  if (l15 == 0) {
    float* mlp = ml + (size_t)part * 128;
    #pragma unroll
    for (int r = 0; r < 4; r++) {
      int row = wq + l4 * 4 + r;
      mlp[row] = mrow[r];
      mlp[64 + row] = lrow[r];
    }
  }
  const size_t pbase = (size_t)part * 4096;
  #pragma unroll
  for (int df = 0; df < 4; df++)
    #pragma unroll
    for (int r = 0; r < 4; r++) {
      float val = o[df][r];
      int row = wq + l4 * 4 + r;
      size_t idx = pbase + (size_t)row * 64 + df * 16 + l15;
      ush hi = f2b(val);
      oph[idx] = hi;
      opl[idx] = f2b(val - b2f(hi));
    }
}

// ---------------------------------------------------------------------------
// Merge the two KV-halves: standard online-softmax combine, write o1 hi/lo.
// ---------------------------------------------------------------------------
__global__ __launch_bounds__(256) void k_attn_merge(
    const ush* __restrict__ oph, const ush* __restrict__ opl,
    const float* __restrict__ ml,
    ush* __restrict__ o1h, ush* __restrict__ o1l)
{
  const int pq = blockIdx.x;              // (pair, qtile)
  const int pair = pq >> 4, qt = pq & 15;
  const int bb = pair / NHEADS, head = pair % NHEADS;
  __shared__ float M0[64], L0[64], M1[64], L1[64];
  const int tid = threadIdx.x;
  const float* mlp = ml + (size_t)pq * 256;
  if (tid < 64) {
    M0[tid] = mlp[tid];        L0[tid] = mlp[64 + tid];
    M1[tid] = mlp[128 + tid];  L1[tid] = mlp[192 + tid];
  }
  __syncthreads();
  const size_t b0 = (size_t)(pq * 2) * 4096;
  const size_t b1 = b0 + 4096;
  #pragma unroll
  for (int e = 0; e < 4; e++) {
    int q4 = e * 256 + tid;               // ushort4 index within 64x64 tile
    int row = q4 >> 4;
    int d4 = (q4 & 15) * 4;
    float m0 = M0[row], l0v = L0[row], m1 = M1[row], l1v = L1[row];
    float m = fmaxf(m0, m1);
    float a0 = __expf(m0 - m), a1 = __expf(m1 - m);
    float inv = 1.0f / (l0v * a0 + l1v * a1);
    ushort4 h0 = *(const ushort4*)(oph + b0 + (size_t)q4 * 4);
    ushort4 g0 = *(const ushort4*)(opl + b0 + (size_t)q4 * 4);
    ushort4 h1 = *(const ushort4*)(oph + b1 + (size_t)q4 * 4);
    ushort4 g1 = *(const ushort4*)(opl + b1 + (size_t)q4 * 4);
    float v0 = ((b2f(h0.x)+b2f(g0.x))*a0 + (b2f(h1.x)+b2f(g1.x))*a1) * inv;
    float v1 = ((b2f(h0.y)+b2f(g0.y))*a0 + (b2f(h1.y)+b2f(g1.y))*a1) * inv;
    float v2 = ((b2f(h0.z)+b2f(g0.z))*a0 + (b2f(h1.z)+b2f(g1.z))*a1) * inv;
    float v3 = ((b2f(h0.w)+b2f(g0.w))*a0 + (b2f(h1.w)+b2f(g1.w))*a1) * inv;
    size_t gidx = ((size_t)(bb * NTOK + qt * 64 + row)) * DIMM + head * HD + d4;
    ushort4 oh, ol;
    oh.x = f2b(v0); ol.x = f2b(v0 - b2f(oh.x));
    oh.y = f2b(v1); ol.y = f2b(v1 - b2f(oh.y));
    oh.z = f2b(v2); ol.z = f2b(v2 - b2f(oh.z));
    oh.w = f2b(v3); ol.w = f2b(v3 - b2f(oh.w));
    *(ushort4*)(o1h + gidx) = oh;
    *(ushort4*)(o1l + gidx) = ol;
  }
}

// ---------------------------------------------------------------------------
extern "C" void kernel_launch(void* const* d_in, const int* in_sizes, int n_in,
                              void* d_out, int out_size, void* d_ws, size_t ws_size,
                              hipStream_t stream)
{
  const float* x      = (const float*)d_in[0];
  const float* qkv_w  = (const float*)d_in[1];
  const float* qkv_b  = (const float*)d_in[2];
  const float* proj_w = (const float*)d_in[3];
  const float* proj_b = (const float*)d_in[4];
  const float* rph    = (const float*)d_in[5];
  const float* rpw    = (const float*)d_in[6];

  char* p = (char*)d_ws;
  ush* xh  = (ush*)p; p += 3145728;   // 2048*768*2   (xh+xl contiguous)
  ush* xl  = (ush*)p; p += 3145728;
  ush* wh  = (ush*)p; p += 3538944;   // 2304*768*2   (wh+wl contiguous)
  ush* wl  = (ush*)p; p += 3538944;   // region reserved (opl overlay), values unused
  ush* pwh = (ush*)p; p += 1179648;   // 768*768*2
  ush* pwl = (ush*)p; p += 1179648;
  ush* qb  = (ush*)p; p += 3145728;   // 24*1024*64*2
  ush* kb  = (ush*)p; p += 3145728;
  ush* vb  = (ush*)p; p += 3145728;
  float* relh = (float*)p; p += 3145728;   // 24*1024*32*4
  float* relw = (float*)p; p += 3145728;
  float* ml   = (float*)p; p += 393216;    // 768*128*4
  (void)wl;
  // Partial O: oph spans xh+xl (3,145,728 ush exact), opl spans wh+wl.
  ush* oph = xh;
  ush* opl = wh;
  // Merge output overlays qb/kb (dead after k_attn_mfma; exact fit).
  ush* o1h = qb;
  ush* o1l = kb;
  float* out = (float*)d_out;

  k_cvt3<<<dim3(3840), dim3(256), 0, stream>>>(x, qkv_w, proj_w,
                                               xh, xl, wh, pwh, pwl);
  k_qkv_mfma<<<dim3(288), dim3(256), 0, stream>>>(xh, xl, wh, qkv_b, qb, kb, vb);
  k_rel<<<dim3(768), dim3(256), 0, stream>>>(qb, rph, rpw, relh, relw);
  k_attn_mfma<<<dim3(768), dim3(256), 0, stream>>>(qb, kb, vb, relh, relw, oph, opl, ml);
  k_attn_merge<<<dim3(384), dim3(256), 0, stream>>>(oph, opl, ml, o1h, o1l);
  k_proj_mfma<<<dim3(384), dim3(256), 0, stream>>>(o1h, o1l, pwh, pwl, proj_b, out);
}